// Round 1
// baseline (298.233 us; speedup 1.0000x reference)
//
#include <hip/hip_runtime.h>

// anchors[MASK] / stride:  [[1.25,1.625],[2.0,3.75],[4.125,2.875]]
__constant__ float c_aw[3] = {1.25f, 2.0f, 4.125f};
__constant__ float c_ah[3] = {1.625f, 3.75f, 2.875f};

// softplus(v) = -log(1 - sigmoid(v)) = log(1+e^v), stable
__device__ __forceinline__ float softplusf(float v) {
    return fmaxf(v, 0.0f) + log1pf(expf(-fabsf(v)));
}

// BCE(sigmoid(v), t) with torch-style clamp(log, -100)
__device__ __forceinline__ float bce_logit(float v, float t) {
    float l1p = fmaxf(-softplusf(v),  -100.0f);  // log(1-p)
    float lp  = fmaxf(-softplusf(-v), -100.0f);  // log(p)
    return -(t * lp + (1.0f - t) * l1p);
}

__device__ __forceinline__ float iou_box(float ax0, float ay0, float ax1, float ay1,
                                         float bx0, float by0, float bx1, float by1) {
    float ltx = fmaxf(ax0, bx0), lty = fmaxf(ay0, by0);
    float rbx = fminf(ax1, bx1), rby = fminf(ay1, by1);
    float iw = fmaxf(rbx - ltx, 0.0f), ih = fmaxf(rby - lty, 0.0f);
    float inter = iw * ih;
    float a1 = (ax1 - ax0) * (ay1 - ay0);
    float a2 = (bx1 - bx0) * (by1 - by0);
    return inter / (a1 + a2 - inter);
}

// ws layout (floats):
// [0] cls_base  [1] obj_base  [2] sx [3] sy [4] sw [5] sh [6] obj_corr
// [7] cls_corr  [8] iou_sum   [9] nmask [10] r50 [11] r75 [12] denom_count

// Dense pass: sum softplus over f==4 (obj) and f in [5,85) (classes).
// Flat layout: idx = ((b*3+a)*2704 + x*52 + y)*85 + f  ->  f = idx % 85.
__global__ void reduce_base(const float4* __restrict__ p4, int n4, float* __restrict__ ws) {
    float acls = 0.0f, aobj = 0.0f;
    int stride = gridDim.x * blockDim.x;
    for (int i = blockIdx.x * blockDim.x + threadIdx.x; i < n4; i += stride) {
        float4 v = p4[i];
        int f0 = (i * 4) % 85;
        float vals[4] = {v.x, v.y, v.z, v.w};
#pragma unroll
        for (int j = 0; j < 4; ++j) {
            int f = f0 + j; if (f >= 85) f -= 85;
            if (f >= 4) {
                float s = fminf(softplusf(vals[j]), 100.0f);
                if (f == 4) aobj += s; else acls += s;
            }
        }
    }
#pragma unroll
    for (int off = 32; off > 0; off >>= 1) {
        acls += __shfl_down(acls, off);
        aobj += __shfl_down(aobj, off);
    }
    if ((threadIdx.x & 63) == 0) {
        atomicAdd(&ws[0], acls);
        atomicAdd(&ws[1], aobj);
    }
}

#define MAXG 256

__global__ void sparse_part(const float* __restrict__ pred, const float* __restrict__ gt,
                            int G, float* __restrict__ ws) {
    __shared__ float s_cx[MAXG], s_cy[MAXG], s_gw[MAXG], s_gh[MAXG], s_sc[MAXG];
    __shared__ int s_ix[MAXG], s_iy[MAXG], s_bs[MAXG], s_lab[MAXG];
    __shared__ unsigned char s_m[3 * MAXG];
    __shared__ float acc[11];
    int tid = threadIdx.x;
    if (tid < 11) acc[tid] = 0.0f;

    for (int g = tid; g < G; g += blockDim.x) {
        float lab = gt[g * 6 + 0];
        float cx  = gt[g * 6 + 1] * 52.0f;
        float cy  = gt[g * 6 + 2] * 52.0f;
        float gw  = gt[g * 6 + 3] * 52.0f;
        float gh  = gt[g * 6 + 4] * 52.0f;
        float bn  = gt[g * 6 + 5];
        s_cx[g] = cx; s_cy[g] = cy; s_gw[g] = gw; s_gh[g] = gh;
        s_ix[g] = (int)floorf(cx); s_iy[g] = (int)floorf(cy);
        s_bs[g] = (int)bn; s_lab[g] = (int)lab;
        s_sc[g] = 2.0f - (gw * 8.0f) * (gh * 8.0f) / 173056.0f;
    }
    __syncthreads();

    // anchor-IoU match (gt box vs anchor box, both centered at (cx,cy))
    for (int t = tid; t < 3 * G; t += blockDim.x) {
        int g = t / 3, a = t % 3;
        float cx = s_cx[g], cy = s_cy[g], gw = s_gw[g], gh = s_gh[g];
        float aw = c_aw[a], ah = c_ah[a];
        float iou = iou_box(cx - gw * 0.5f, cy - gh * 0.5f, cx + gw * 0.5f, cy + gh * 0.5f,
                            cx - aw * 0.5f, cy - ah * 0.5f, cx + aw * 0.5f, cy + ah * 0.5f);
        s_m[t] = (iou > 0.3f) ? 1 : 0;
    }
    __syncthreads();

    for (int t = tid; t < 3 * G; t += blockDim.x) {
        if (!s_m[t]) continue;
        int g = t / 3, a = t % 3;
        int ix = s_ix[g], iy = s_iy[g], bs = s_bs[g];
        float cx = s_cx[g], cy = s_cy[g], gw = s_gw[g], gh = s_gh[g], sc = s_sc[g];
        float aw = c_aw[a], ah = c_ah[a];
        int base = ((bs * 3 + a) * 2704 + ix * 52 + iy) * 85;
        float v0 = pred[base + 0], v1 = pred[base + 1], v2 = pred[base + 2];
        float v3 = pred[base + 3], v4 = pred[base + 4];
        // reference quirk: predx adds the H-axis grid (iy), predy adds ix
        float px = 1.0f / (1.0f + expf(-v0)) + (float)iy;
        float py = 1.0f / (1.0f + expf(-v1)) + (float)ix;
        float pw = expf(v2) * aw;
        float ph = expf(v3) * ah;
        float pg = iou_box(cx - gw * 0.5f, cy - gh * 0.5f, cx + gw * 0.5f, cy + gh * 0.5f,
                           px - pw * 0.5f, py - ph * 0.5f, px + pw * 0.5f, py + ph * 0.5f);
        atomicAdd(&acc[7], 1.0f);                 // nmask
        atomicAdd(&acc[6], (1.0f - pg) * sc);     // iou loss sum
        if (pg > 0.5f)  atomicAdd(&acc[8], 1.0f); // recall50 numerator
        if (pg > 0.75f) atomicAdd(&acc[9], 1.0f); // recall75 numerator

        // last-write-wins owner of cell (bs, a, ix, iy)
        bool owner = true;
        for (int g2 = g + 1; g2 < G; ++g2) {
            if (s_m[g2 * 3 + a] && s_bs[g2] == bs && s_ix[g2] == ix && s_iy[g2] == iy) {
                owner = false; break;
            }
        }
        if (owner) {
            float tx = cx - floorf(cx);
            float ty = cy - floorf(cy);
            float ow = logf(gw / aw);
            float oh = logf(gh / ah);
            atomicAdd(&acc[0], sc * bce_logit(v0, tx));
            atomicAdd(&acc[1], sc * bce_logit(v1, ty));
            float dw = v2 * sc - ow * sc;
            float dh = v3 * sc - oh * sc;
            atomicAdd(&acc[2], dw * dw);
            atomicAdd(&acc[3], dh * dh);
            atomicAdd(&acc[4], bce_logit(v4, 1.0f) - bce_logit(v4, 0.0f));
        }

        // unique (cell, label) representative for classes correction + denom
        int lab = s_lab[g];
        bool rep = true;
        for (int g2 = g + 1; g2 < G; ++g2) {
            if (s_m[g2 * 3 + a] && s_bs[g2] == bs && s_ix[g2] == ix && s_iy[g2] == iy &&
                s_lab[g2] == lab) {
                rep = false; break;
            }
        }
        if (rep) {
            float vc = pred[base + 5 + lab];
            atomicAdd(&acc[5], bce_logit(vc, 1.0f) - bce_logit(vc, 0.0f));
            atomicAdd(&acc[10], 1.0f);
        }
    }
    __syncthreads();
    if (tid == 0) {
        for (int k = 0; k < 11; ++k) ws[2 + k] = acc[k];
    }
}

__global__ void finalize_k(const float* __restrict__ ws, float* __restrict__ out) {
    if (threadIdx.x == 0 && blockIdx.x == 0) {
        const float NCELL = 259584.0f;      // 32*3*52*52
        const float NCLSE = 20766720.0f;    // *80
        float lossx = ws[2] / NCELL;
        float lossy = ws[3] / NCELL;
        float lossw = ws[4] / NCELL;
        float lossh = ws[5] / NCELL;
        float lossobj = (ws[1] + ws[6]) / NCELL;
        float losscls = (ws[0] + ws[7]) / NCLSE;
        float nmask = ws[9];
        float lossiou = (nmask > 0.0f) ? (ws[8] / fmaxf(nmask, 1.0f)) : 0.0f;
        float denom = ws[12] + 1e-10f;
        float r50 = ws[10] / denom;
        float r75 = ws[11] / denom;
        float loss = lossx + lossy + lossw + lossh + lossobj + losscls + lossiou;
        out[0] = loss;  out[1] = lossx;   out[2] = lossy;   out[3] = lossw; out[4] = lossh;
        out[5] = lossobj; out[6] = losscls; out[7] = lossiou; out[8] = r50; out[9] = r75;
    }
}

extern "C" void kernel_launch(void* const* d_in, const int* in_sizes, int n_in,
                              void* d_out, int out_size, void* d_ws, size_t ws_size,
                              hipStream_t stream) {
    const float* pred = (const float*)d_in[0];
    const float* gtp  = (const float*)d_in[1];
    float* out = (float*)d_out;
    float* ws  = (float*)d_ws;
    int ntot = in_sizes[0];          // 22,056,960
    int G    = in_sizes[1] / 6;      // 200

    hipMemsetAsync(d_ws, 0, 16 * sizeof(float), stream);
    int n4 = ntot / 4;
    reduce_base<<<2048, 256, 0, stream>>>((const float4*)pred, n4, ws);
    sparse_part<<<1, 640, 0, stream>>>(pred, gtp, G, ws);
    finalize_k<<<1, 64, 0, stream>>>(ws, out);
}